// Round 3
// baseline (404.839 us; speedup 1.0000x reference)
//
#include <hip/hip_runtime.h>
#include <hip/hip_fp16.h>

#define NLAB 30000
#define HID  1024
#define NB   256
#define NE   (NLAB - 1)

#define RECB   256               // rec-specialist blocks (pure gather)
#define ROWB   256               // row blocks (one full batch row each)
#define BLOCKS (RECB + ROWB)
#define NL4    (NLAB / 4)        // 7500 float4 per row
#define QBASE  8192              // edges [0,8192) static (2 per rec wave); rest queued
#define CUROFF 16384             // byte offset of steal cursor in ws (slots end at 12288)

// float block reduce, 1024 threads (16 waves)
__device__ __forceinline__ float blockReduceSum1024(float v) {
#pragma unroll
    for (int off = 32; off > 0; off >>= 1)
        v += __shfl_down(v, off, 64);
    __shared__ float smr[16];
    const int lane = threadIdx.x & 63;
    const int wid  = threadIdx.x >> 6;
    __syncthreads();
    if (lane == 0) smr[wid] = v;
    __syncthreads();
    float r = 0.f;
    if (threadIdx.x == 0) {
#pragma unroll
        for (int i = 0; i < 16; ++i) r += smr[i];
    }
    return r;
}

__device__ __forceinline__ double blockReduceSumD256(double v) {
#pragma unroll
    for (int off = 32; off > 0; off >>= 1)
        v += __shfl_down(v, off, 64);
    __shared__ double smd[4];
    const int lane = threadIdx.x & 63;
    const int wid  = threadIdx.x >> 6;
    __syncthreads();
    if (lane == 0) smd[wid] = v;
    __syncthreads();
    double r = 0.0;
    if (threadIdx.x == 0) r = smd[0] + smd[1] + smd[2] + smd[3];
    return r;
}

__device__ __forceinline__ float sqdiff4(const float4 a, const float4 b) {
    const float dx = a.x - b.x, dy = a.y - b.y;
    const float dz = a.z - b.z, dw = a.w - b.w;
    return dx * dx + dy * dy + dz * dz + dw * dw;
}

// One edge: 8 x 1KB coalesced loads (lane*16B), sqdiff accumulated in regs.
// Offsets 0/1KB/2KB/3KB fold into global_load imm offsets.
__device__ __forceinline__ float do_edge(const float* __restrict__ params,
                                         int pr, int cr, int lane) {
    const float4* pa = (const float4*)params + ((size_t)pr << 8) + lane;
    const float4* ca = (const float4*)params + ((size_t)cr << 8) + lane;
    float s = sqdiff4(pa[0],   ca[0]);
    s      += sqdiff4(pa[64],  ca[64]);
    s      += sqdiff4(pa[128], ca[128]);
    s      += sqdiff4(pa[192], ca[192]);
    return s;
}

// ---------------------------------------------------------------------------
// Work-stealing gather. Each grab = 2 edges (pair base). One-grab lookahead:
// the atomic for the NEXT pair is issued before processing the CURRENT pair,
// so its ~us device-scope latency hides under the 16KB of gather loads.
// `statics` = this wave's static first pair base, or -1 for queue-only waves.
// Self-balancing at 16KB granularity; all blocks retire within ~one grab.
// ---------------------------------------------------------------------------
__device__ __forceinline__ float steal_gather(const float* __restrict__ params,
                                              const int* __restrict__ pidx,
                                              const int* __restrict__ cidx,
                                              int* cursor, int lane,
                                              int statics) {
    float recs = 0.f;
    int base = statics;
    if (base < 0) {
        int nraw = 0;
        if (lane == 0) nraw = atomicAdd(cursor, 1);
        base = QBASE + 2 * __builtin_amdgcn_readfirstlane(nraw);
    }
    while (base < NE) {
        int nraw = 0;
        if (lane == 0) nraw = atomicAdd(cursor, 1);          // prefetch next pair
        recs += do_edge(params, pidx[base], cidx[base], lane);
        if (base + 1 < NE)
            recs += do_edge(params, pidx[base + 1], cidx[base + 1], lane);
        base = QBASE + 2 * __builtin_amdgcn_readfirstlane(nraw);
    }
    return recs;
}

// ---------------------------------------------------------------------------
// Phase-parallel specialization + dynamic gather:
//   blocks [0,256):   rec specialists — 2 static edges per wave, then steal.
//   blocks [256,512): row blocks — full batch row: BCE + fp16 sigmoid row in
//                     LDS + prob over ALL edges; then join the steal queue
//                     (provably non-empty when they arrive).
// ---------------------------------------------------------------------------
__global__ __launch_bounds__(1024, 2)
void fused_kernel(const float4* __restrict__ lg4,
                  const float4* __restrict__ tg4,
                  const float* __restrict__ params,
                  const int* __restrict__ pidx,
                  const int* __restrict__ cidx,
                  double* __restrict__ slots,
                  int* __restrict__ cursor) {
    __shared__ __attribute__((aligned(16))) char smem[60032];
    __half* sprob = (__half*)smem;    // 30000 halves = 60000 B (row blocks)

    const int tid  = threadIdx.x;
    const int bid  = blockIdx.x;
    const int lane = tid & 63;
    const int wid  = tid >> 6;

    float bces = 0.f, recs = 0.f, ps = 0.f;

    if (bid < RECB) {
        // ---- rec specialist: static pair, then steal. Zero barriers. ----
        const int w = bid * 16 + wid;                 // 0..4095
        recs = steal_gather(params, pidx, cidx, cursor, lane, 2 * w);
    } else {
        const int j = bid - RECB;     // row index
        // ---- row phase: full-row sigmoid staging + BCE ----
        {
            const float4* lrow = lg4 + (size_t)j * NL4;
            const float4* trow = tg4 + (size_t)j * NL4;
            for (int i = tid; i < NL4; i += 1024) {
                const float4 l = lrow[i];
                const float4 t = trow[i];
                const float e0 = __expf(-fabsf(l.x)), i0 = __frcp_rn(1.f + e0);
                const float e1 = __expf(-fabsf(l.y)), i1 = __frcp_rn(1.f + e1);
                const float e2 = __expf(-fabsf(l.z)), i2 = __frcp_rn(1.f + e2);
                const float e3 = __expf(-fabsf(l.w)), i3 = __frcp_rn(1.f + e3);
                const float s0 = l.x > 0.f ? i0 : 1.f - i0;
                const float s1 = l.y > 0.f ? i1 : 1.f - i1;
                const float s2 = l.z > 0.f ? i2 : 1.f - i2;
                const float s3 = l.w > 0.f ? i3 : 1.f - i3;
                sprob[4 * i + 0] = __float2half(s0);
                sprob[4 * i + 1] = __float2half(s1);
                sprob[4 * i + 2] = __float2half(s2);
                sprob[4 * i + 3] = __float2half(s3);
                // softplus(l) = max(l,0) - log(sigmoid(|l|))
                bces += fmaxf(l.x, 0.f) - __logf(i0) - l.x * t.x;
                bces += fmaxf(l.y, 0.f) - __logf(i1) - l.y * t.y;
                bces += fmaxf(l.z, 0.f) - __logf(i2) - l.z * t.z;
                bces += fmaxf(l.w, 0.f) - __logf(i3) - l.w * t.w;
            }
            __syncthreads();
            // ---- prob_reg over ALL edges from LDS ----
            for (int e = tid; e < NE; e += 1024) {
                const float d = __half2float(sprob[cidx[e]]) -
                                __half2float(sprob[pidx[e]]);
                ps += d > 0.f ? d : 0.f;
            }
            // no barrier: stealing never touches LDS, and blockReduceSum1024
            // begins with its own __syncthreads()
        }
        // ---- join the steal queue ----
        recs = steal_gather(params, pidx, cidx, cursor, lane, -1);
    }

    const float rb = blockReduceSum1024(bces);
    const float rr = blockReduceSum1024(recs);
    const float rp = blockReduceSum1024(ps);
    if (tid == 0) {
        slots[bid]              = (double)rb;
        slots[BLOCKS + bid]     = (double)rr;
        slots[2 * BLOCKS + bid] = (double)rp;
    }
}

// finalize: sum the 3 slot arrays, combine, write scalar
__global__ void fin_kernel(const double* __restrict__ slots,
                           float* __restrict__ out) {
    double sb = 0.0, sr = 0.0, sp = 0.0;
    for (int i = threadIdx.x; i < BLOCKS; i += 256) {
        sb += slots[i];
        sr += slots[BLOCKS + i];
        sp += slots[2 * BLOCKS + i];
    }
    sb = blockReduceSumD256(sb);
    sr = blockReduceSumD256(sr);
    sp = blockReduceSumD256(sp);
    if (threadIdx.x == 0) {
        const double bce = sb * (1.0 / ((double)NB * (double)NLAB));
        out[0] = (float)(bce + 5e-5 * sr + 1e-4 * sp);
    }
}

extern "C" void kernel_launch(void* const* d_in, const int* in_sizes, int n_in,
                              void* d_out, int out_size, void* d_ws, size_t ws_size,
                              hipStream_t stream) {
    const float* logits  = (const float*)d_in[0];
    const float* targets = (const float*)d_in[1];
    const float* params  = (const float*)d_in[2];
    const int*   pidx    = (const int*)d_in[3];
    const int*   cidx    = (const int*)d_in[4];
    double* slots  = (double*)d_ws;
    int*    cursor = (int*)((char*)d_ws + CUROFF);
    float*  out    = (float*)d_out;

    hipMemsetAsync(cursor, 0, 4, stream);   // re-poison-safe queue init
    fused_kernel<<<BLOCKS, 1024, 0, stream>>>(
        (const float4*)logits, (const float4*)targets, params,
        pidx, cidx, slots, cursor);
    fin_kernel<<<1, 256, 0, stream>>>(slots, out);
}

// Round 4
// 237.430 us; speedup vs baseline: 1.7051x; 1.7051x over previous
//
#include <hip/hip_runtime.h>
#include <hip/hip_fp16.h>

#define NLAB 30000
#define HID  1024
#define NB   256
#define NE   (NLAB - 1)

#define ROWB   256               // row blocks (one full batch row each)
#define RECB2  640               // rec blocks (gather only, no LDS use)
#define BLOCKS (ROWB + RECB2)    // 896: 384-block backfill pool over 512 residency
#define NL4    (NLAB / 4)        // 7500 float4 per row
#define RWAVES (RECB2 * 16)      // 10240 rec waves; 29999/10240 = 2.93 edges/wave

// float block reduce, 1024 threads (16 waves)
__device__ __forceinline__ float blockReduceSum1024(float v) {
#pragma unroll
    for (int off = 32; off > 0; off >>= 1)
        v += __shfl_down(v, off, 64);
    __shared__ float smr[16];
    const int lane = threadIdx.x & 63;
    const int wid  = threadIdx.x >> 6;
    __syncthreads();
    if (lane == 0) smr[wid] = v;
    __syncthreads();
    float r = 0.f;
    if (threadIdx.x == 0) {
#pragma unroll
        for (int i = 0; i < 16; ++i) r += smr[i];
    }
    return r;
}

__device__ __forceinline__ double blockReduceSumD256(double v) {
#pragma unroll
    for (int off = 32; off > 0; off >>= 1)
        v += __shfl_down(v, off, 64);
    __shared__ double smd[4];
    const int lane = threadIdx.x & 63;
    const int wid  = threadIdx.x >> 6;
    __syncthreads();
    if (lane == 0) smd[wid] = v;
    __syncthreads();
    double r = 0.0;
    if (threadIdx.x == 0) r = smd[0] + smd[1] + smd[2] + smd[3];
    return r;
}

__device__ __forceinline__ float sqdiff4(const float4 a, const float4 b) {
    const float dx = a.x - b.x, dy = a.y - b.y;
    const float dz = a.z - b.z, dw = a.w - b.w;
    return dx * dx + dy * dy + dz * dz + dw * dw;
}

// One edge: 8 x 1KB coalesced loads (lane*16B), sqdiff accumulated in regs.
// Offsets 0/1KB/2KB/3KB fold into global_load imm offsets.
__device__ __forceinline__ float do_edge(const float* __restrict__ params,
                                         int pr, int cr, int lane) {
    const float4* pa = (const float4*)params + ((size_t)pr << 8) + lane;
    const float4* ca = (const float4*)params + ((size_t)cr << 8) + lane;
    float s = sqdiff4(pa[0],   ca[0]);
    s      += sqdiff4(pa[64],  ca[64]);
    s      += sqdiff4(pa[128], ca[128]);
    s      += sqdiff4(pa[192], ca[192]);
    return s;
}

// ---------------------------------------------------------------------------
// Interleaved static gather, zero barriers, zero atomics (R3's contended
// cursor serialized the grid — reverted). Global rec-wave g takes edges
// g, g+RWAVES, g+2*RWAVES (2 or 3 edges: +-1 on ~3 => +-2% per-block spread).
// Edge indices lane-prefetched (one coalesced load, __shfl broadcast).
// ---------------------------------------------------------------------------
__device__ __forceinline__ float rec_wave(const float* __restrict__ params,
                                          const int* __restrict__ pidx,
                                          const int* __restrict__ cidx,
                                          int g, int lane) {
    const int mycnt = (NE - g + RWAVES - 1) / RWAVES;   // 2 or 3
    int pv = 0, cv = 0;
    if (lane < mycnt) {
        const int e = g + lane * RWAVES;
        pv = pidx[e];
        cv = cidx[e];
    }
    float recs = 0.f;
    for (int k = 0; k < mycnt; ++k) {
        const int pr = __shfl(pv, k, 64);
        const int cr = __shfl(cv, k, 64);
        recs += do_edge(params, pr, cr, lane);
    }
    return recs;
}

// ---------------------------------------------------------------------------
// Role split + backfill pool:
//   bids [0,512) alternate: even -> rec block r=bid>>1 (0..255),
//                           odd  -> row block j=bid>>1 (0..255)
//   bids [512,896) -> rec blocks r=bid-256 (256..639), scheduled as earlier
//   blocks retire (backfill keeps wave slots full through the tail).
// Row blocks do row+prob ONLY and retire early, freeing slots+LDS.
// ---------------------------------------------------------------------------
__global__ __launch_bounds__(1024, 2)
void fused_kernel(const float4* __restrict__ lg4,
                  const float4* __restrict__ tg4,
                  const float* __restrict__ params,
                  const int* __restrict__ pidx,
                  const int* __restrict__ cidx,
                  double* __restrict__ slots) {
    __shared__ __attribute__((aligned(16))) char smem[60032];
    __half* sprob = (__half*)smem;    // 30000 halves = 60000 B (row blocks)

    const int tid  = threadIdx.x;
    const int bid  = blockIdx.x;
    const int lane = tid & 63;
    const int wid  = tid >> 6;

    // role decode
    const bool isrow = (bid < 512) && (bid & 1);
    const int  rrec  = (bid < 512) ? (bid >> 1) : (bid - 256);  // 0..639
    const int  jrow  = bid >> 1;                                 // 0..255

    float bces = 0.f, recs = 0.f, ps = 0.f;

    if (!isrow) {
        // ---- rec block: gather immediately, zero barriers ----
        recs = rec_wave(params, pidx, cidx, rrec * 16 + wid, lane);
    } else {
        // ---- row phase: full-row sigmoid staging + BCE ----
        {
            const float4* lrow = lg4 + (size_t)jrow * NL4;
            const float4* trow = tg4 + (size_t)jrow * NL4;
            for (int i = tid; i < NL4; i += 1024) {
                const float4 l = lrow[i];
                const float4 t = trow[i];
                const float e0 = __expf(-fabsf(l.x)), i0 = __frcp_rn(1.f + e0);
                const float e1 = __expf(-fabsf(l.y)), i1 = __frcp_rn(1.f + e1);
                const float e2 = __expf(-fabsf(l.z)), i2 = __frcp_rn(1.f + e2);
                const float e3 = __expf(-fabsf(l.w)), i3 = __frcp_rn(1.f + e3);
                const float s0 = l.x > 0.f ? i0 : 1.f - i0;
                const float s1 = l.y > 0.f ? i1 : 1.f - i1;
                const float s2 = l.z > 0.f ? i2 : 1.f - i2;
                const float s3 = l.w > 0.f ? i3 : 1.f - i3;
                sprob[4 * i + 0] = __float2half(s0);
                sprob[4 * i + 1] = __float2half(s1);
                sprob[4 * i + 2] = __float2half(s2);
                sprob[4 * i + 3] = __float2half(s3);
                // softplus(l) = max(l,0) - log(sigmoid(|l|))
                bces += fmaxf(l.x, 0.f) - __logf(i0) - l.x * t.x;
                bces += fmaxf(l.y, 0.f) - __logf(i1) - l.y * t.y;
                bces += fmaxf(l.z, 0.f) - __logf(i2) - l.z * t.z;
                bces += fmaxf(l.w, 0.f) - __logf(i3) - l.w * t.w;
            }
            __syncthreads();
            // ---- prob_reg over ALL edges from LDS ----
            for (int e = tid; e < NE; e += 1024) {
                const float d = __half2float(sprob[cidx[e]]) -
                                __half2float(sprob[pidx[e]]);
                ps += d > 0.f ? d : 0.f;
            }
        }
        // retire: freed slots are backfilled by pool rec blocks
    }

    const float rb = blockReduceSum1024(bces);
    const float rr = blockReduceSum1024(recs);
    const float rp = blockReduceSum1024(ps);
    if (tid == 0) {
        slots[bid]              = (double)rb;
        slots[BLOCKS + bid]     = (double)rr;
        slots[2 * BLOCKS + bid] = (double)rp;
    }
}

// finalize: sum the 3 slot arrays, combine, write scalar
__global__ void fin_kernel(const double* __restrict__ slots,
                           float* __restrict__ out) {
    double sb = 0.0, sr = 0.0, sp = 0.0;
    for (int i = threadIdx.x; i < BLOCKS; i += 256) {
        sb += slots[i];
        sr += slots[BLOCKS + i];
        sp += slots[2 * BLOCKS + i];
    }
    sb = blockReduceSumD256(sb);
    sr = blockReduceSumD256(sr);
    sp = blockReduceSumD256(sp);
    if (threadIdx.x == 0) {
        const double bce = sb * (1.0 / ((double)NB * (double)NLAB));
        out[0] = (float)(bce + 5e-5 * sr + 1e-4 * sp);
    }
}

extern "C" void kernel_launch(void* const* d_in, const int* in_sizes, int n_in,
                              void* d_out, int out_size, void* d_ws, size_t ws_size,
                              hipStream_t stream) {
    const float* logits  = (const float*)d_in[0];
    const float* targets = (const float*)d_in[1];
    const float* params  = (const float*)d_in[2];
    const int*   pidx    = (const int*)d_in[3];
    const int*   cidx    = (const int*)d_in[4];
    double* slots = (double*)d_ws;
    float*  out   = (float*)d_out;

    fused_kernel<<<BLOCKS, 1024, 0, stream>>>(
        (const float4*)logits, (const float4*)targets, params,
        pidx, cidx, slots);
    fin_kernel<<<1, 256, 0, stream>>>(slots, out);
}